// Round 14
// baseline (28.777 us; speedup 1.0000x reference)
//
#include <hip/hip_runtime.h>
#include <math.h>

typedef __fp16 h2 __attribute__((ext_vector_type(2)));
typedef __fp16 h8 __attribute__((ext_vector_type(8)));
union H8 { h8 v; h2 p[4]; };

#define H_IN   136
#define W_IN   200
#define HWP    (H_IN * W_IN)       // 27200
#define OH     272
#define OW     400
#define RB     8                   // low-res rows per strip (17 strips)
#define NSTRIP 17
#define LROWS  (RB + 1)            // +1 halo row above
#define CH     8
#define CIN    8
#define NPARAM 169
#define NEG_LOG2E (-1.4426950408889634f)

// R14: ONE lever vs R13 — weight reads from LDS vectorized. Same dup'd-h2
// values, but laid out 16B-aligned per output channel and read as
// ds_read_b128 (h8 = 4 dup'd weights/read): 47 LDS reads/unit vs 169.
// Theory: the 169 broadcast ds_read_b32 occupied the per-CU LDS pipe
// ~13us chip-wide — the real phase-1 bound (explains R13's shortfall).
// Math bit-identical to R13 -> absmax must stay 0.00390625.
//
// LDS h2-index layout:
//  [0..95]    L0W[o][12]: wx, wy, fw0..7, pad, pad   (row = 48B, aligned)
//  [96..159]  L1W[o][8]
//  [160..167] L2W[8]  (pre-scaled by -log2e)
//  [168..175] B0[8]
//  [176..183] B1[8]
//  [184]      b2      (pre-scaled)

__device__ __forceinline__ h2 pkrtz(float a, float b) {
    return __builtin_amdgcn_cvt_pkrtz(a, b);
}

__global__ __launch_bounds__(256, 3) void mask_head_fused(
    const float* __restrict__ mask_feats,   // (N, 8, H, W)
    const float* __restrict__ params,       // (n_inst, 169)
    const float* __restrict__ locations,    // (n_inst, 2)
    const int*   __restrict__ im_inds,      // (n_inst,)
    const int*   __restrict__ fpn_levels,   // (n_inst,)
    const float* __restrict__ soi_tab,      // (5,)
    float* __restrict__ out)                // (n_inst, 272, 400)
{
    __shared__ __align__(16) h2 sWV[192];
    __shared__ float T[LROWS][W_IN];        // t = -log2e * logit

    const int inst = blockIdx.y;
    const int r0   = blockIdx.x * RB;
    const int tid  = threadIdx.x;

    const float* P = params + inst * NPARAM;
    if (tid < 185) {
        float w;
        if (tid < 96)       { const int o = tid / 12, i = tid - o * 12;
                              w = (i < 10) ? P[o * 10 + i] : 0.0f; }
        else if (tid < 160) { w = P[80 + (tid - 96)]; }
        else if (tid < 168) { w = NEG_LOG2E * P[144 + (tid - 160)]; }
        else if (tid < 176) { w = P[152 + (tid - 168)]; }
        else if (tid < 184) { w = P[160 + (tid - 176)]; }
        else                { w = NEG_LOG2E * P[168]; }
        const __fp16 hw = (__fp16)w;
        h2 v; v.x = hw; v.y = hw;
        sWV[tid] = v;
    }

    const float loc_x   = locations[2 * inst];
    const float loc_y   = locations[2 * inst + 1];
    const float inv_soi = 1.0f / soi_tab[fpn_levels[inst]];
    const float* F = mask_feats + (size_t)im_inds[inst] * (CIN * HWP);
    float* O = out + (size_t)inst * (OH * OW);
    __syncthreads();

    // ---- Phase 1: 225 units of 8 px (4 half2 slots), packed fp16 MLP ----
    if (tid < LROWS * (W_IN / 8)) {
        const int k = tid / 25;
        const int c = (tid - k * 25) * 8;
        const int r = min(max(r0 - 1 + k, 0), H_IN - 1);

        // features -> fp16 pairs
        h2 f[CIN][4];
        #pragma unroll
        for (int ch = 0; ch < CIN; ++ch) {
            const float* q = F + ch * HWP + r * W_IN + c;
            const float4 A = *(const float4*)q;
            const float4 B = *(const float4*)(q + 4);
            f[ch][0] = pkrtz(A.x, A.y); f[ch][1] = pkrtz(A.z, A.w);
            f[ch][2] = pkrtz(B.x, B.y); f[ch][3] = pkrtz(B.z, B.w);
        }

        // rel coords -> fp16 pairs
        const float ry  = (loc_y - (float)(r * 8 + 4)) * inv_soi;
        const float dx  = -8.0f * inv_soi;
        const float rx0 = (loc_x - (float)(c * 8 + 4)) * inv_soi;
        h2 rxh[4];
        #pragma unroll
        for (int s = 0; s < 4; ++s)
            rxh[s] = pkrtz(rx0 + (float)(2 * s) * dx, rx0 + (float)(2 * s + 1) * dx);
        const h2 ryh = pkrtz(ry, ry);
        const h2 z2  = {(__fp16)0.0f, (__fp16)0.0f};

        // bias / layer-2 weight vectors (7 vector reads, shared by all layers)
        H8 vB0a, vB0b, vB1a, vB1b, vL2a, vL2b;
        vB0a.v = *(const h8*)&sWV[168]; vB0b.v = *(const h8*)&sWV[172];
        vB1a.v = *(const h8*)&sWV[176]; vB1b.v = *(const h8*)&sWV[180];
        vL2a.v = *(const h8*)&sWV[160]; vL2b.v = *(const h8*)&sWV[164];
        const h2 b2 = sWV[184];

        // layer 0: 10 -> 8, relu  (3 b128 weight reads per o)
        h2 h0[CH][4];
        #pragma unroll
        for (int o = 0; o < CH; ++o) {
            H8 wa, wb, wc;
            wa.v = *(const h8*)&sWV[o * 12];
            wb.v = *(const h8*)&sWV[o * 12 + 4];
            wc.v = *(const h8*)&sWV[o * 12 + 8];
            const h2 b0o  = (o < 4) ? vB0a.p[o] : vB0b.p[o - 4];
            const h2 base = __builtin_elementwise_fma(wa.p[1], ryh, b0o);
            h2 a[4];
            #pragma unroll
            for (int s = 0; s < 4; ++s) a[s] = __builtin_elementwise_fma(wa.p[0], rxh[s], base);
            const h2 fw[8] = {wa.p[2], wa.p[3], wb.p[0], wb.p[1],
                              wb.p[2], wb.p[3], wc.p[0], wc.p[1]};
            #pragma unroll
            for (int i = 0; i < CIN; ++i) {
                #pragma unroll
                for (int s = 0; s < 4; ++s) a[s] = __builtin_elementwise_fma(fw[i], f[i][s], a[s]);
            }
            #pragma unroll
            for (int s = 0; s < 4; ++s) h0[o][s] = __builtin_elementwise_max(a[s], z2);
        }

        // layer 1: 8 -> 8, relu  (2 b128 weight reads per o)
        h2 h1[CH][4];
        #pragma unroll
        for (int o = 0; o < CH; ++o) {
            H8 wa, wb;
            wa.v = *(const h8*)&sWV[96 + o * 8];
            wb.v = *(const h8*)&sWV[96 + o * 8 + 4];
            const h2 b1o = (o < 4) ? vB1a.p[o] : vB1b.p[o - 4];
            h2 a[4] = {b1o, b1o, b1o, b1o};
            const h2 w[8] = {wa.p[0], wa.p[1], wa.p[2], wa.p[3],
                             wb.p[0], wb.p[1], wb.p[2], wb.p[3]};
            #pragma unroll
            for (int i = 0; i < CH; ++i) {
                #pragma unroll
                for (int s = 0; s < 4; ++s) a[s] = __builtin_elementwise_fma(w[i], h0[i][s], a[s]);
            }
            #pragma unroll
            for (int s = 0; s < 4; ++s) h1[o][s] = __builtin_elementwise_max(a[s], z2);
        }

        // layer 2: 8 -> 1 (weights pre-scaled by -log2e at staging)
        h2 t[4] = {b2, b2, b2, b2};
        const h2 w2[8] = {vL2a.p[0], vL2a.p[1], vL2a.p[2], vL2a.p[3],
                          vL2b.p[0], vL2b.p[1], vL2b.p[2], vL2b.p[3]};
        #pragma unroll
        for (int i = 0; i < CH; ++i) {
            #pragma unroll
            for (int s = 0; s < 4; ++s) t[s] = __builtin_elementwise_fma(w2[i], h1[i][s], t[s]);
        }

        *(float4*)&T[k][c] = make_float4((float)t[0].x, (float)t[0].y,
                                         (float)t[1].x, (float)t[1].y);
        *(float4*)&T[k][c + 4] = make_float4((float)t[2].x, (float)t[2].y,
                                             (float)t[3].x, (float)t[3].y);
    }
    __syncthreads();

    // ---- Phase 2: 400 units of 16 px (8 wide x 2 output rows) — as R8 ----
    #pragma unroll
    for (int it = 0; it < 2; ++it) {
        const int s = tid + 256 * it;
        if (s < RB * (W_IN / 4)) {
            const int rpl = s / (W_IN / 4);         // 0..7
            const int t   = s - rpl * (W_IN / 4);   // 0..49
            const int cm  = 4 * t;
            const int cl  = max(cm - 1, 0);

            const float4 mR = *(const float4*)&T[rpl + 1][cm];
            const float4 mQ = *(const float4*)&T[rpl][cm];
            const float  AR = T[rpl + 1][cl];       // == mR.x when t==0
            const float  AQ = T[rpl][cl];

            const float Aa = 0.5f * (AR + AQ);
            const float Ba = 0.5f * (mR.x + mQ.x);
            const float Ca = 0.5f * (mR.y + mQ.y);
            const float Da = 0.5f * (mR.z + mQ.z);
            const float Ea = 0.5f * (mR.w + mQ.w);

            float4 s0, s1, s2, s3;
            s0.x = __builtin_amdgcn_rcpf(1.0f + __builtin_amdgcn_exp2f(0.5f * (Aa + Ba)));
            s0.y = __builtin_amdgcn_rcpf(1.0f + __builtin_amdgcn_exp2f(Ba));
            s0.z = __builtin_amdgcn_rcpf(1.0f + __builtin_amdgcn_exp2f(0.5f * (Ba + Ca)));
            s0.w = __builtin_amdgcn_rcpf(1.0f + __builtin_amdgcn_exp2f(Ca));
            s1.x = __builtin_amdgcn_rcpf(1.0f + __builtin_amdgcn_exp2f(0.5f * (Ca + Da)));
            s1.y = __builtin_amdgcn_rcpf(1.0f + __builtin_amdgcn_exp2f(Da));
            s1.z = __builtin_amdgcn_rcpf(1.0f + __builtin_amdgcn_exp2f(0.5f * (Da + Ea)));
            s1.w = __builtin_amdgcn_rcpf(1.0f + __builtin_amdgcn_exp2f(Ea));

            s2.x = __builtin_amdgcn_rcpf(1.0f + __builtin_amdgcn_exp2f(0.5f * (AR + mR.x)));
            s2.y = __builtin_amdgcn_rcpf(1.0f + __builtin_amdgcn_exp2f(mR.x));
            s2.z = __builtin_amdgcn_rcpf(1.0f + __builtin_amdgcn_exp2f(0.5f * (mR.x + mR.y)));
            s2.w = __builtin_amdgcn_rcpf(1.0f + __builtin_amdgcn_exp2f(mR.y));
            s3.x = __builtin_amdgcn_rcpf(1.0f + __builtin_amdgcn_exp2f(0.5f * (mR.y + mR.z)));
            s3.y = __builtin_amdgcn_rcpf(1.0f + __builtin_amdgcn_exp2f(mR.z));
            s3.z = __builtin_amdgcn_rcpf(1.0f + __builtin_amdgcn_exp2f(0.5f * (mR.z + mR.w)));
            s3.w = __builtin_amdgcn_rcpf(1.0f + __builtin_amdgcn_exp2f(mR.w));

            float* O0 = O + (size_t)(2 * (r0 + rpl)) * OW + 8 * t;
            *(float4*)(O0)          = s0;
            *(float4*)(O0 + 4)      = s1;
            *(float4*)(O0 + OW)     = s2;
            *(float4*)(O0 + OW + 4) = s3;
        }
    }
}

extern "C" void kernel_launch(void* const* d_in, const int* in_sizes, int n_in,
                              void* d_out, int out_size, void* d_ws, size_t ws_size,
                              hipStream_t stream) {
    const float* mask_feats = (const float*)d_in[0];
    const float* params     = (const float*)d_in[1];
    const float* locations  = (const float*)d_in[2];
    const int*   im_inds    = (const int*)d_in[3];
    const int*   fpn_levels = (const int*)d_in[4];
    const float* soi_tab    = (const float*)d_in[5];

    const int n_inst = in_sizes[1] / NPARAM;   // 128
    dim3 grid(NSTRIP, n_inst);                 // (17, 128)
    mask_head_fused<<<grid, 256, 0, stream>>>(
        mask_feats, params, locations, im_inds, fpn_levels, soi_tab, (float*)d_out);
}